// Round 1
// baseline (734.976 us; speedup 1.0000x reference)
//
#include <hip/hip_runtime.h>

#define N_NODES 100000
#define N_EDGES 1600000
#define E_TOT   (N_EDGES + N_NODES)

static __device__ __forceinline__ float lrelu(float z) { return z > 0.f ? z : 0.2f * z; }

// ---------------- CSR build ----------------
__global__ void count_kernel(const int* __restrict__ ei, int* __restrict__ cnt) {
    int t = blockIdx.x * 256 + threadIdx.x;
    if (t >= E_TOT) return;
    int d = (t < N_EDGES) ? ei[N_EDGES + t] : (t - N_EDGES);
    atomicAdd(&cnt[d], 1);
}

__global__ void scan1(const int* __restrict__ cnt, int* __restrict__ offs, int* __restrict__ bsum) {
    __shared__ int s[256];
    int t = threadIdx.x, i = blockIdx.x * 256 + t;
    int v = (i < N_NODES) ? cnt[i] : 0;
    s[t] = v; __syncthreads();
    for (int d = 1; d < 256; d <<= 1) {
        int a = (t >= d) ? s[t - d] : 0; __syncthreads();
        s[t] += a; __syncthreads();
    }
    if (i < N_NODES) offs[i] = s[t] - v;   // block-local exclusive
    if (t == 255) bsum[blockIdx.x] = s[255];
}

__global__ void scan2(int* __restrict__ bsum, int nb) {
    __shared__ int s[512];
    int t = threadIdx.x;
    int v = (t < nb) ? bsum[t] : 0;
    s[t] = v; __syncthreads();
    for (int d = 1; d < 512; d <<= 1) {
        int a = (t >= d) ? s[t - d] : 0; __syncthreads();
        s[t] += a; __syncthreads();
    }
    if (t < nb) bsum[t] = s[t] - v;        // exclusive block offsets
}

__global__ void scan3(int* __restrict__ offs, const int* __restrict__ bsum, int* __restrict__ cursor) {
    int i = blockIdx.x * 256 + threadIdx.x;
    if (i < N_NODES) {
        int o = offs[i] + bsum[i >> 8];
        offs[i] = o;
        cursor[i] = o;
    }
    if (i == 0) offs[N_NODES] = E_TOT;
}

__global__ void scatter_kernel(const int* __restrict__ ei, int* __restrict__ cursor, int* __restrict__ srcs) {
    int t = blockIdx.x * 256 + threadIdx.x;
    if (t >= E_TOT) return;
    int s, d;
    if (t < N_EDGES) { s = ei[t]; d = ei[N_EDGES + t]; }
    else             { s = d = t - N_EDGES; }
    int pos = atomicAdd(&cursor[d], 1);
    srcs[pos] = s;
}

// ---------------- fused GEMM + attention logits ----------------
// thread-per-node; x tile staged in LDS (pad 33 breaks bank conflicts);
// W rows are wave-uniform -> scalar loads; acc[OUT] in VGPRs.
template <int IN, int OUT, int HEADS>
__global__ __launch_bounds__(256) void gemm_al(const float* __restrict__ x, const float* __restrict__ W,
                                               const float* __restrict__ asrc, const float* __restrict__ adst,
                                               float* __restrict__ h, float* __restrict__ als,
                                               float* __restrict__ ald) {
    constexpr int KC = 32;
    constexpr int NCH = IN / KC;
    constexpr int C = OUT / HEADS;
    __shared__ float sx[256 * 33];
    int t = threadIdx.x;
    int n = blockIdx.x * 256 + t;

    float acc[OUT];
#pragma unroll
    for (int j = 0; j < OUT; ++j) acc[j] = 0.f;

    for (int kc = 0; kc < NCH; ++kc) {
        __syncthreads();
        int col = t & 31;
        int r0 = t >> 5;                      // 0..7
#pragma unroll
        for (int i = 0; i < 32; ++i) {
            int r = r0 + 8 * i;               // 0..255
            int row = blockIdx.x * 256 + r;
            if (row >= N_NODES) row = N_NODES - 1;
            sx[r * 33 + col] = x[(long)row * IN + kc * KC + col];
        }
        __syncthreads();
#pragma unroll
        for (int k = 0; k < KC; ++k) {
            float xv = sx[t * 33 + k];
            const float* Wr = W + (kc * KC + k) * OUT;  // wave-uniform
#pragma unroll
            for (int j = 0; j < OUT; ++j) acc[j] = fmaf(xv, Wr[j], acc[j]);
        }
    }

    if (n < N_NODES) {
#pragma unroll
        for (int j = 0; j < OUT; j += 4) {
            float4 v = make_float4(acc[j], acc[j + 1], acc[j + 2], acc[j + 3]);
            *reinterpret_cast<float4*>(&h[(long)n * OUT + j]) = v;
        }
#pragma unroll
        for (int hd = 0; hd < HEADS; ++hd) {
            float ps = 0.f, pd = 0.f;
#pragma unroll
            for (int c = 0; c < C; ++c) {
                ps = fmaf(acc[hd * C + c], asrc[hd * C + c], ps);
                pd = fmaf(acc[hd * C + c], adst[hd * C + c], pd);
            }
            als[n * HEADS + hd] = ps;
            ald[n * HEADS + hd] = pd;
        }
    }
}

// ---------------- aggregation, H=4 C=16 (wave per dst node, lane = head*16+ch) ----------------
__global__ __launch_bounds__(256) void agg_h4(const int* __restrict__ offs, const int* __restrict__ srcs,
                                              const float* __restrict__ h, const float* __restrict__ als,
                                              const float* __restrict__ ald, const float* __restrict__ bias,
                                              float* __restrict__ g, int do_relu) {
    int wid = threadIdx.x >> 6, lane = threadIdx.x & 63;
    int n = blockIdx.x * 4 + wid;
    if (n >= N_NODES) return;
    int hd = lane >> 4;
    float ad = ald[n * 4 + hd];
    int e0 = offs[n], e1 = offs[n + 1];
    float acc = 0.f, den = 0.f;
    int e = e0;
    for (; e + 1 < e1; e += 2) {
        int s0 = srcs[e], s1 = srcs[e + 1];
        float as0 = als[s0 * 4 + hd];
        float as1 = als[s1 * 4 + hd];
        float h0 = h[(long)s0 * 64 + lane];
        float h1 = h[(long)s1 * 64 + lane];
        float w0 = __expf(lrelu(as0 + ad));
        float w1 = __expf(lrelu(as1 + ad));
        den += w0 + w1;
        acc = fmaf(w0, h0, acc);
        acc = fmaf(w1, h1, acc);
    }
    if (e < e1) {
        int s0 = srcs[e];
        float w0 = __expf(lrelu(als[s0 * 4 + hd] + ad));
        den += w0;
        acc = fmaf(w0, h[(long)s0 * 64 + lane], acc);
    }
    float o = acc / den + bias[lane];
    if (do_relu) o = fmaxf(o, 0.f);
    g[(long)n * 64 + lane] = o;
}

// ---------------- aggregation, H=1 C=32 (wave per dst node, 2 edges in flight) ----------------
__global__ __launch_bounds__(256) void agg_h1(const int* __restrict__ offs, const int* __restrict__ srcs,
                                              const float* __restrict__ h3, const float* __restrict__ als,
                                              const float* __restrict__ ald, const float* __restrict__ bias,
                                              float* __restrict__ out) {
    int wid = threadIdx.x >> 6, lane = threadIdx.x & 63;
    int n = blockIdx.x * 4 + wid;
    if (n >= N_NODES) return;
    int half = lane >> 5, c = lane & 31;
    float ad = ald[n];
    int e0 = offs[n], e1 = offs[n + 1];
    float acc = 0.f, den = 0.f;
    for (int e = e0 + half; e < e1; e += 2) {
        int s = srcs[e];
        float w = __expf(lrelu(als[s] + ad));
        den += w;
        acc = fmaf(w, h3[(long)s * 32 + c], acc);
    }
    acc += __shfl_xor(acc, 32);
    den += __shfl_xor(den, 32);
    if (half == 0) out[(long)n * 32 + c] = acc / den + bias[c];
}

extern "C" void kernel_launch(void* const* d_in, const int* in_sizes, int n_in,
                              void* d_out, int out_size, void* d_ws, size_t ws_size,
                              hipStream_t stream) {
    (void)in_sizes; (void)n_in; (void)out_size; (void)ws_size;
    const float* x   = (const float*)d_in[0];
    const int*   ei  = (const int*)d_in[1];
    const float* W1  = (const float*)d_in[2];
    const float* as1 = (const float*)d_in[3];
    const float* ad1 = (const float*)d_in[4];
    const float* b1  = (const float*)d_in[5];
    const float* W2  = (const float*)d_in[6];
    const float* as2 = (const float*)d_in[7];
    const float* ad2 = (const float*)d_in[8];
    const float* b2  = (const float*)d_in[9];
    const float* W3  = (const float*)d_in[10];
    const float* as3 = (const float*)d_in[11];
    const float* ad3 = (const float*)d_in[12];
    const float* b3  = (const float*)d_in[13];
    float* out = (float*)d_out;

    char* w = (char*)d_ws;
    auto alloc = [&](size_t bytes) {
        void* p = (void*)w;
        w += (bytes + 255) & ~(size_t)255;
        return p;
    };
    int*   cnt    = (int*)alloc((size_t)N_NODES * 4);
    int*   offs   = (int*)alloc((size_t)(N_NODES + 1) * 4);
    int*   bsum   = (int*)alloc(512 * 4);
    int*   cursor = (int*)alloc((size_t)N_NODES * 4);
    int*   srcs   = (int*)alloc((size_t)E_TOT * 4);
    float* h      = (float*)alloc((size_t)N_NODES * 64 * 4);
    float* g      = (float*)alloc((size_t)N_NODES * 64 * 4);
    float* als    = (float*)alloc((size_t)N_NODES * 4 * 4);
    float* ald    = (float*)alloc((size_t)N_NODES * 4 * 4);

    hipMemsetAsync(cnt, 0, (size_t)N_NODES * 4, stream);

    int gE = (E_TOT + 255) / 256;
    int gN = (N_NODES + 255) / 256;   // 391
    count_kernel<<<gE, 256, 0, stream>>>(ei, cnt);
    scan1<<<gN, 256, 0, stream>>>(cnt, offs, bsum);
    scan2<<<1, 512, 0, stream>>>(bsum, gN);
    scan3<<<gN, 256, 0, stream>>>(offs, bsum, cursor);
    scatter_kernel<<<gE, 256, 0, stream>>>(ei, cursor, srcs);

    // layer 1: x[100000,128] @ W1[128,64], H=4
    gemm_al<128, 64, 4><<<gN, 256, 0, stream>>>(x, W1, as1, ad1, h, als, ald);
    agg_h4<<<N_NODES / 4, 256, 0, stream>>>(offs, srcs, h, als, ald, b1, g, 1);
    // layer 2: g[100000,64] @ W2[64,64], H=4
    gemm_al<64, 64, 4><<<gN, 256, 0, stream>>>(g, W2, as2, ad2, h, als, ald);
    agg_h4<<<N_NODES / 4, 256, 0, stream>>>(offs, srcs, h, als, ald, b2, g, 1);
    // layer 3: g[100000,64] @ W3[64,32], H=1 -> d_out
    gemm_al<64, 32, 1><<<gN, 256, 0, stream>>>(g, W3, as3, ad3, h, als, ald);
    agg_h1<<<N_NODES / 4, 256, 0, stream>>>(offs, srcs, h, als, ald, b3, out);
}

// Round 2
// 691.029 us; speedup vs baseline: 1.0636x; 1.0636x over previous
//
#include <hip/hip_runtime.h>

#define N_NODES 100000
#define N_EDGES 1600000
#define E_TOT   (N_EDGES + N_NODES)
#define NPART   8
#define PART_SZ (N_NODES / NPART)   // 12500
#define PART_BLOCKS 256             // blocks per partition

static __device__ __forceinline__ float lrelu(float z) { return z > 0.f ? z : 0.2f * z; }

// ---------------- CSR build (XCD-partitioned by dst range) ----------------
// partition = blockIdx & 7 -> round-robin XCD heuristic: all atomics/stores of a
// partition stay in ONE XCD's L2 (contiguous dst range), killing the cross-XCD
// line ping-pong that caused 108 MB of writeback for a 6.8 MB buffer.
__global__ __launch_bounds__(256) void csr_count(const int* __restrict__ ei, int* __restrict__ cnt) {
    int part = blockIdx.x & (NPART - 1);
    int lo = part * PART_SZ, hi = lo + PART_SZ;
    int stride = (gridDim.x / NPART) * 256;
    for (int t = (blockIdx.x / NPART) * 256 + threadIdx.x; t < E_TOT; t += stride) {
        int d = (t < N_EDGES) ? ei[N_EDGES + t] : (t - N_EDGES);
        if (d >= lo && d < hi) atomicAdd(&cnt[d], 1);
    }
}

__global__ __launch_bounds__(256) void csr_scatter(const int* __restrict__ ei, int* __restrict__ cursor,
                                                   int* __restrict__ srcs) {
    int part = blockIdx.x & (NPART - 1);
    int lo = part * PART_SZ, hi = lo + PART_SZ;
    int stride = (gridDim.x / NPART) * 256;
    for (int t = (blockIdx.x / NPART) * 256 + threadIdx.x; t < E_TOT; t += stride) {
        int s, d;
        if (t < N_EDGES) { d = ei[N_EDGES + t]; s = ei[t]; }
        else             { s = d = t - N_EDGES; }
        if (d >= lo && d < hi) {
            int pos = atomicAdd(&cursor[d], 1);
            srcs[pos] = s;
        }
    }
}

__global__ void scan1(const int* __restrict__ cnt, int* __restrict__ offs, int* __restrict__ bsum) {
    __shared__ int s[256];
    int t = threadIdx.x, i = blockIdx.x * 256 + t;
    int v = (i < N_NODES) ? cnt[i] : 0;
    s[t] = v; __syncthreads();
    for (int d = 1; d < 256; d <<= 1) {
        int a = (t >= d) ? s[t - d] : 0; __syncthreads();
        s[t] += a; __syncthreads();
    }
    if (i < N_NODES) offs[i] = s[t] - v;   // block-local exclusive
    if (t == 255) bsum[blockIdx.x] = s[255];
}

__global__ void scan2(int* __restrict__ bsum, int nb) {
    __shared__ int s[512];
    int t = threadIdx.x;
    int v = (t < nb) ? bsum[t] : 0;
    s[t] = v; __syncthreads();
    for (int d = 1; d < 512; d <<= 1) {
        int a = (t >= d) ? s[t - d] : 0; __syncthreads();
        s[t] += a; __syncthreads();
    }
    if (t < nb) bsum[t] = s[t] - v;        // exclusive block offsets
}

__global__ void scan3(int* __restrict__ offs, const int* __restrict__ bsum, int* __restrict__ cursor) {
    int i = blockIdx.x * 256 + threadIdx.x;
    if (i < N_NODES) {
        int o = offs[i] + bsum[i >> 8];
        offs[i] = o;
        cursor[i] = o;
    }
    if (i == 0) offs[N_NODES] = E_TOT;
}

// ---------------- fused GEMM + attention logits ----------------
template <int IN, int OUT, int HEADS>
__global__ __launch_bounds__(256) void gemm_al(const float* __restrict__ x, const float* __restrict__ W,
                                               const float* __restrict__ asrc, const float* __restrict__ adst,
                                               float* __restrict__ h, float* __restrict__ als,
                                               float* __restrict__ ald) {
    constexpr int KC = 32;
    constexpr int NCH = IN / KC;
    constexpr int C = OUT / HEADS;
    __shared__ float sx[256 * 33];
    int t = threadIdx.x;
    int n = blockIdx.x * 256 + t;

    float acc[OUT];
#pragma unroll
    for (int j = 0; j < OUT; ++j) acc[j] = 0.f;

    for (int kc = 0; kc < NCH; ++kc) {
        __syncthreads();
        int col = t & 31;
        int r0 = t >> 5;
#pragma unroll
        for (int i = 0; i < 32; ++i) {
            int r = r0 + 8 * i;
            int row = blockIdx.x * 256 + r;
            if (row >= N_NODES) row = N_NODES - 1;
            sx[r * 33 + col] = x[(long)row * IN + kc * KC + col];
        }
        __syncthreads();
#pragma unroll
        for (int k = 0; k < KC; ++k) {
            float xv = sx[t * 33 + k];
            const float* Wr = W + (kc * KC + k) * OUT;  // wave-uniform -> scalar loads
#pragma unroll
            for (int j = 0; j < OUT; ++j) acc[j] = fmaf(xv, Wr[j], acc[j]);
        }
    }

    if (n < N_NODES) {
#pragma unroll
        for (int j = 0; j < OUT; j += 4) {
            float4 v = make_float4(acc[j], acc[j + 1], acc[j + 2], acc[j + 3]);
            *reinterpret_cast<float4*>(&h[(long)n * OUT + j]) = v;
        }
#pragma unroll
        for (int hd = 0; hd < HEADS; ++hd) {
            float ps = 0.f, pd = 0.f;
#pragma unroll
            for (int c = 0; c < C; ++c) {
                ps = fmaf(acc[hd * C + c], asrc[hd * C + c], ps);
                pd = fmaf(acc[hd * C + c], adst[hd * C + c], pd);
            }
            als[n * HEADS + hd] = ps;
            ald[n * HEADS + hd] = pd;
        }
    }
}

// ---------------- aggregation, H=4 C=16 (wave per dst node, lane = head*16+ch) ----------------
__global__ __launch_bounds__(256) void agg_h4(const int* __restrict__ offs, const int* __restrict__ srcs,
                                              const float* __restrict__ h, const float* __restrict__ als,
                                              const float* __restrict__ ald, const float* __restrict__ bias,
                                              float* __restrict__ g, int do_relu) {
    int wid = threadIdx.x >> 6, lane = threadIdx.x & 63;
    int n = blockIdx.x * 4 + wid;
    if (n >= N_NODES) return;
    int hd = lane >> 4;
    float ad = ald[n * 4 + hd];
    int e0 = offs[n], e1 = offs[n + 1];
    float acc = 0.f, den = 0.f;
    int e = e0;
    for (; e + 1 < e1; e += 2) {
        int s0 = srcs[e], s1 = srcs[e + 1];
        float as0 = als[s0 * 4 + hd];
        float as1 = als[s1 * 4 + hd];
        float h0 = h[(long)s0 * 64 + lane];
        float h1 = h[(long)s1 * 64 + lane];
        float w0 = __expf(lrelu(as0 + ad));
        float w1 = __expf(lrelu(as1 + ad));
        den += w0 + w1;
        acc = fmaf(w0, h0, acc);
        acc = fmaf(w1, h1, acc);
    }
    if (e < e1) {
        int s0 = srcs[e];
        float w0 = __expf(lrelu(als[s0 * 4 + hd] + ad));
        den += w0;
        acc = fmaf(w0, h[(long)s0 * 64 + lane], acc);
    }
    float o = acc / den + bias[lane];
    if (do_relu) o = fmaxf(o, 0.f);
    g[(long)n * 64 + lane] = o;
}

// ---------------- aggregation, H=1 C=32 ----------------
__global__ __launch_bounds__(256) void agg_h1(const int* __restrict__ offs, const int* __restrict__ srcs,
                                              const float* __restrict__ h3, const float* __restrict__ als,
                                              const float* __restrict__ ald, const float* __restrict__ bias,
                                              float* __restrict__ out) {
    int wid = threadIdx.x >> 6, lane = threadIdx.x & 63;
    int n = blockIdx.x * 4 + wid;
    if (n >= N_NODES) return;
    int half = lane >> 5, c = lane & 31;
    float ad = ald[n];
    int e0 = offs[n], e1 = offs[n + 1];
    float acc = 0.f, den = 0.f;
    for (int e = e0 + half; e < e1; e += 2) {
        int s = srcs[e];
        float w = __expf(lrelu(als[s] + ad));
        den += w;
        acc = fmaf(w, h3[(long)s * 32 + c], acc);
    }
    acc += __shfl_xor(acc, 32);
    den += __shfl_xor(den, 32);
    if (half == 0) out[(long)n * 32 + c] = acc / den + bias[c];
}

extern "C" void kernel_launch(void* const* d_in, const int* in_sizes, int n_in,
                              void* d_out, int out_size, void* d_ws, size_t ws_size,
                              hipStream_t stream) {
    (void)in_sizes; (void)n_in; (void)out_size; (void)ws_size;
    const float* x   = (const float*)d_in[0];
    const int*   ei  = (const int*)d_in[1];
    const float* W1  = (const float*)d_in[2];
    const float* as1 = (const float*)d_in[3];
    const float* ad1 = (const float*)d_in[4];
    const float* b1  = (const float*)d_in[5];
    const float* W2  = (const float*)d_in[6];
    const float* as2 = (const float*)d_in[7];
    const float* ad2 = (const float*)d_in[8];
    const float* b2  = (const float*)d_in[9];
    const float* W3  = (const float*)d_in[10];
    const float* as3 = (const float*)d_in[11];
    const float* ad3 = (const float*)d_in[12];
    const float* b3  = (const float*)d_in[13];
    float* out = (float*)d_out;

    char* w = (char*)d_ws;
    auto alloc = [&](size_t bytes) {
        void* p = (void*)w;
        w += (bytes + 255) & ~(size_t)255;
        return p;
    };
    int*   cnt    = (int*)alloc((size_t)N_NODES * 4);
    int*   offs   = (int*)alloc((size_t)(N_NODES + 1) * 4);
    int*   bsum   = (int*)alloc(512 * 4);
    int*   cursor = (int*)alloc((size_t)N_NODES * 4);
    int*   srcs   = (int*)alloc((size_t)E_TOT * 4);
    float* h      = (float*)alloc((size_t)N_NODES * 64 * 4);
    float* g      = (float*)alloc((size_t)N_NODES * 64 * 4);
    float* als    = (float*)alloc((size_t)N_NODES * 4 * 4);
    float* ald    = (float*)alloc((size_t)N_NODES * 4 * 4);

    hipMemsetAsync(cnt, 0, (size_t)N_NODES * 4, stream);

    int gN = (N_NODES + 255) / 256;   // 391
    csr_count<<<NPART * PART_BLOCKS, 256, 0, stream>>>(ei, cnt);
    scan1<<<gN, 256, 0, stream>>>(cnt, offs, bsum);
    scan2<<<1, 512, 0, stream>>>(bsum, gN);
    scan3<<<gN, 256, 0, stream>>>(offs, bsum, cursor);
    csr_scatter<<<NPART * PART_BLOCKS, 256, 0, stream>>>(ei, cursor, srcs);

    // layer 1: x[100000,128] @ W1[128,64], H=4
    gemm_al<128, 64, 4><<<gN, 256, 0, stream>>>(x, W1, as1, ad1, h, als, ald);
    agg_h4<<<N_NODES / 4, 256, 0, stream>>>(offs, srcs, h, als, ald, b1, g, 1);
    // layer 2: g[100000,64] @ W2[64,64], H=4
    gemm_al<64, 64, 4><<<gN, 256, 0, stream>>>(g, W2, as2, ad2, h, als, ald);
    agg_h4<<<N_NODES / 4, 256, 0, stream>>>(offs, srcs, h, als, ald, b2, g, 1);
    // layer 3: g[100000,64] @ W3[64,32], H=1 -> d_out
    gemm_al<64, 32, 1><<<gN, 256, 0, stream>>>(g, W3, as3, ad3, h, als, ald);
    agg_h1<<<N_NODES / 4, 256, 0, stream>>>(offs, srcs, h, als, ald, b3, out);
}

// Round 3
// 571.576 us; speedup vs baseline: 1.2859x; 1.2090x over previous
//
#include <hip/hip_runtime.h>

#define N_NODES 100000
#define N_EDGES 1600000
#define E_TOT   (N_EDGES + N_NODES)
#define NPART   8
#define PART_SZ (N_NODES / NPART)   // 12500
#define PART_BLOCKS 256             // blocks per partition

static __device__ __forceinline__ float lrelu(float z) { return z > 0.f ? z : 0.2f * z; }

// ---------------- CSR build (XCD-partitioned by dst range) ----------------
// partition = blockIdx & 7 -> round-robin XCD heuristic: all atomics/stores of a
// partition stay in ONE XCD's L2 (contiguous dst range). This killed the 108 MB
// cross-XCD writeback seen in round 1 (WRITE_SIZE 108 MB -> 25 MB total).
__global__ __launch_bounds__(256) void csr_count(const int* __restrict__ ei, int* __restrict__ cnt) {
    int part = blockIdx.x & (NPART - 1);
    int lo = part * PART_SZ, hi = lo + PART_SZ;
    int stride = (gridDim.x / NPART) * 256;
    for (int t = (blockIdx.x / NPART) * 256 + threadIdx.x; t < E_TOT; t += stride) {
        int d = (t < N_EDGES) ? ei[N_EDGES + t] : (t - N_EDGES);
        if (d >= lo && d < hi) atomicAdd(&cnt[d], 1);
    }
}

__global__ __launch_bounds__(256) void csr_scatter(const int* __restrict__ ei, int* __restrict__ cursor,
                                                   int* __restrict__ srcs) {
    int part = blockIdx.x & (NPART - 1);
    int lo = part * PART_SZ, hi = lo + PART_SZ;
    int stride = (gridDim.x / NPART) * 256;
    for (int t = (blockIdx.x / NPART) * 256 + threadIdx.x; t < E_TOT; t += stride) {
        int d = (t < N_EDGES) ? ei[N_EDGES + t] : (t - N_EDGES);
        if (d >= lo && d < hi) {
            int s = (t < N_EDGES) ? ei[t] : d;   // src load only when committed
            int pos = atomicAdd(&cursor[d], 1);
            srcs[pos] = s;
        }
    }
}

__global__ void scan1(const int* __restrict__ cnt, int* __restrict__ offs, int* __restrict__ bsum) {
    __shared__ int s[256];
    int t = threadIdx.x, i = blockIdx.x * 256 + t;
    int v = (i < N_NODES) ? cnt[i] : 0;
    s[t] = v; __syncthreads();
    for (int d = 1; d < 256; d <<= 1) {
        int a = (t >= d) ? s[t - d] : 0; __syncthreads();
        s[t] += a; __syncthreads();
    }
    if (i < N_NODES) offs[i] = s[t] - v;   // block-local exclusive
    if (t == 255) bsum[blockIdx.x] = s[255];
}

__global__ void scan2(int* __restrict__ bsum, int nb) {
    __shared__ int s[512];
    int t = threadIdx.x;
    int v = (t < nb) ? bsum[t] : 0;
    s[t] = v; __syncthreads();
    for (int d = 1; d < 512; d <<= 1) {
        int a = (t >= d) ? s[t - d] : 0; __syncthreads();
        s[t] += a; __syncthreads();
    }
    if (t < nb) bsum[t] = s[t] - v;        // exclusive block offsets
}

__global__ void scan3(int* __restrict__ offs, const int* __restrict__ bsum, int* __restrict__ cursor) {
    int i = blockIdx.x * 256 + threadIdx.x;
    if (i < N_NODES) {
        int o = offs[i] + bsum[i >> 8];
        offs[i] = o;
        cursor[i] = o;
    }
    if (i == 0) offs[N_NODES] = E_TOT;
}

// ---------------- fused GEMM + attention logits ----------------
template <int IN, int OUT, int HEADS>
__global__ __launch_bounds__(256) void gemm_al(const float* __restrict__ x, const float* __restrict__ W,
                                               const float* __restrict__ asrc, const float* __restrict__ adst,
                                               float* __restrict__ h, float* __restrict__ als,
                                               float* __restrict__ ald) {
    constexpr int KC = 32;
    constexpr int NCH = IN / KC;
    constexpr int C = OUT / HEADS;
    __shared__ float sx[256 * 33];
    int t = threadIdx.x;
    int n = blockIdx.x * 256 + t;

    float acc[OUT];
#pragma unroll
    for (int j = 0; j < OUT; ++j) acc[j] = 0.f;

    for (int kc = 0; kc < NCH; ++kc) {
        __syncthreads();
        int col = t & 31;
        int r0 = t >> 5;
#pragma unroll
        for (int i = 0; i < 32; ++i) {
            int r = r0 + 8 * i;
            int row = blockIdx.x * 256 + r;
            if (row >= N_NODES) row = N_NODES - 1;
            sx[r * 33 + col] = x[(long)row * IN + kc * KC + col];
        }
        __syncthreads();
#pragma unroll
        for (int k = 0; k < KC; ++k) {
            float xv = sx[t * 33 + k];
            const float* Wr = W + (kc * KC + k) * OUT;  // wave-uniform -> scalar loads
#pragma unroll
            for (int j = 0; j < OUT; ++j) acc[j] = fmaf(xv, Wr[j], acc[j]);
        }
    }

    if (n < N_NODES) {
#pragma unroll
        for (int j = 0; j < OUT; j += 4) {
            float4 v = make_float4(acc[j], acc[j + 1], acc[j + 2], acc[j + 3]);
            *reinterpret_cast<float4*>(&h[(long)n * OUT + j]) = v;
        }
#pragma unroll
        for (int hd = 0; hd < HEADS; ++hd) {
            float ps = 0.f, pd = 0.f;
#pragma unroll
            for (int c = 0; c < C; ++c) {
                ps = fmaf(acc[hd * C + c], asrc[hd * C + c], ps);
                pd = fmaf(acc[hd * C + c], adst[hd * C + c], pd);
            }
            als[n * HEADS + hd] = ps;
            ald[n * HEADS + hd] = pd;
        }
    }
}

// ---------------- aggregation, H=4 C=16 ----------------
// wave per dst node; q=lane>>4 = edge slot (4 edges in flight),
// cc=lane&15 = float4 channel slice (16 lanes x 16B = full 64-ch row).
// ~5 VALU + 0.75 mem-instr per edge (vs ~20 VALU + 3 loads in round 2).
__global__ __launch_bounds__(256) void agg_h4(const int* __restrict__ offs, const int* __restrict__ srcs,
                                              const float* __restrict__ h, const float* __restrict__ als,
                                              const float* __restrict__ ald, const float* __restrict__ bias,
                                              float* __restrict__ g, int do_relu) {
    int wid = threadIdx.x >> 6, lane = threadIdx.x & 63;
    int n = blockIdx.x * 4 + wid;
    if (n >= N_NODES) return;
    int q = lane >> 4, cc = lane & 15;
    int hd = cc >> 2;
    float ad = ald[n * 4 + hd];
    int e0 = offs[n], e1 = offs[n + 1];   // e1 > e0 always (self-loop)
    float4 acc = make_float4(0.f, 0.f, 0.f, 0.f);
    float den = 0.f;
    for (int e = e0; e < e1; e += 4) {
        int ee = e + q;
        int idx = (ee < e1) ? ee : (e1 - 1);
        int s = srcs[idx];
        float w = __expf(lrelu(als[s * 4 + hd] + ad));
        w = (ee < e1) ? w : 0.f;
        float4 hv = *reinterpret_cast<const float4*>(&h[(long)s * 64 + cc * 4]);
        den += w;
        acc.x = fmaf(w, hv.x, acc.x);
        acc.y = fmaf(w, hv.y, acc.y);
        acc.z = fmaf(w, hv.z, acc.z);
        acc.w = fmaf(w, hv.w, acc.w);
    }
    // reduce across the 4 edge slots (lanes with equal cc)
    acc.x += __shfl_xor(acc.x, 16); acc.y += __shfl_xor(acc.y, 16);
    acc.z += __shfl_xor(acc.z, 16); acc.w += __shfl_xor(acc.w, 16);
    den += __shfl_xor(den, 16);
    acc.x += __shfl_xor(acc.x, 32); acc.y += __shfl_xor(acc.y, 32);
    acc.z += __shfl_xor(acc.z, 32); acc.w += __shfl_xor(acc.w, 32);
    den += __shfl_xor(den, 32);
    if (q == 0) {
        float4 b4 = *reinterpret_cast<const float4*>(&bias[cc * 4]);
        float inv = 1.f / den;
        float4 o;
        o.x = fmaf(acc.x, inv, b4.x);
        o.y = fmaf(acc.y, inv, b4.y);
        o.z = fmaf(acc.z, inv, b4.z);
        o.w = fmaf(acc.w, inv, b4.w);
        if (do_relu) {
            o.x = fmaxf(o.x, 0.f); o.y = fmaxf(o.y, 0.f);
            o.z = fmaxf(o.z, 0.f); o.w = fmaxf(o.w, 0.f);
        }
        *reinterpret_cast<float4*>(&g[(long)n * 64 + cc * 4]) = o;
    }
}

// ---------------- aggregation, H=1 C=32 ----------------
// 8 edges in flight: q=lane>>3, cc=lane&7 (8 lanes x float4 = full 32-ch row).
__global__ __launch_bounds__(256) void agg_h1(const int* __restrict__ offs, const int* __restrict__ srcs,
                                              const float* __restrict__ h3, const float* __restrict__ als,
                                              const float* __restrict__ ald, const float* __restrict__ bias,
                                              float* __restrict__ out) {
    int wid = threadIdx.x >> 6, lane = threadIdx.x & 63;
    int n = blockIdx.x * 4 + wid;
    if (n >= N_NODES) return;
    int q = lane >> 3, cc = lane & 7;
    float ad = ald[n];
    int e0 = offs[n], e1 = offs[n + 1];
    float4 acc = make_float4(0.f, 0.f, 0.f, 0.f);
    float den = 0.f;
    for (int e = e0; e < e1; e += 8) {
        int ee = e + q;
        int idx = (ee < e1) ? ee : (e1 - 1);
        int s = srcs[idx];
        float w = __expf(lrelu(als[s] + ad));
        w = (ee < e1) ? w : 0.f;
        float4 hv = *reinterpret_cast<const float4*>(&h3[(long)s * 32 + cc * 4]);
        den += w;
        acc.x = fmaf(w, hv.x, acc.x);
        acc.y = fmaf(w, hv.y, acc.y);
        acc.z = fmaf(w, hv.z, acc.z);
        acc.w = fmaf(w, hv.w, acc.w);
    }
    acc.x += __shfl_xor(acc.x, 8);  acc.y += __shfl_xor(acc.y, 8);
    acc.z += __shfl_xor(acc.z, 8);  acc.w += __shfl_xor(acc.w, 8);
    den += __shfl_xor(den, 8);
    acc.x += __shfl_xor(acc.x, 16); acc.y += __shfl_xor(acc.y, 16);
    acc.z += __shfl_xor(acc.z, 16); acc.w += __shfl_xor(acc.w, 16);
    den += __shfl_xor(den, 16);
    acc.x += __shfl_xor(acc.x, 32); acc.y += __shfl_xor(acc.y, 32);
    acc.z += __shfl_xor(acc.z, 32); acc.w += __shfl_xor(acc.w, 32);
    den += __shfl_xor(den, 32);
    if (q == 0) {
        float4 b4 = *reinterpret_cast<const float4*>(&bias[cc * 4]);
        float inv = 1.f / den;
        float4 o;
        o.x = fmaf(acc.x, inv, b4.x);
        o.y = fmaf(acc.y, inv, b4.y);
        o.z = fmaf(acc.z, inv, b4.z);
        o.w = fmaf(acc.w, inv, b4.w);
        *reinterpret_cast<float4*>(&out[(long)n * 32 + cc * 4]) = o;
    }
}

extern "C" void kernel_launch(void* const* d_in, const int* in_sizes, int n_in,
                              void* d_out, int out_size, void* d_ws, size_t ws_size,
                              hipStream_t stream) {
    (void)in_sizes; (void)n_in; (void)out_size; (void)ws_size;
    const float* x   = (const float*)d_in[0];
    const int*   ei  = (const int*)d_in[1];
    const float* W1  = (const float*)d_in[2];
    const float* as1 = (const float*)d_in[3];
    const float* ad1 = (const float*)d_in[4];
    const float* b1  = (const float*)d_in[5];
    const float* W2  = (const float*)d_in[6];
    const float* as2 = (const float*)d_in[7];
    const float* ad2 = (const float*)d_in[8];
    const float* b2  = (const float*)d_in[9];
    const float* W3  = (const float*)d_in[10];
    const float* as3 = (const float*)d_in[11];
    const float* ad3 = (const float*)d_in[12];
    const float* b3  = (const float*)d_in[13];
    float* out = (float*)d_out;

    char* w = (char*)d_ws;
    auto alloc = [&](size_t bytes) {
        void* p = (void*)w;
        w += (bytes + 255) & ~(size_t)255;
        return p;
    };
    int*   cnt    = (int*)alloc((size_t)N_NODES * 4);
    int*   offs   = (int*)alloc((size_t)(N_NODES + 1) * 4);
    int*   bsum   = (int*)alloc(512 * 4);
    int*   cursor = (int*)alloc((size_t)N_NODES * 4);
    int*   srcs   = (int*)alloc((size_t)E_TOT * 4);
    float* h      = (float*)alloc((size_t)N_NODES * 64 * 4);
    float* g      = (float*)alloc((size_t)N_NODES * 64 * 4);
    float* als    = (float*)alloc((size_t)N_NODES * 4 * 4);
    float* ald    = (float*)alloc((size_t)N_NODES * 4 * 4);

    hipMemsetAsync(cnt, 0, (size_t)N_NODES * 4, stream);

    int gN = (N_NODES + 255) / 256;   // 391
    csr_count<<<NPART * PART_BLOCKS, 256, 0, stream>>>(ei, cnt);
    scan1<<<gN, 256, 0, stream>>>(cnt, offs, bsum);
    scan2<<<1, 512, 0, stream>>>(bsum, gN);
    scan3<<<gN, 256, 0, stream>>>(offs, bsum, cursor);
    csr_scatter<<<NPART * PART_BLOCKS, 256, 0, stream>>>(ei, cursor, srcs);

    // layer 1: x[100000,128] @ W1[128,64], H=4
    gemm_al<128, 64, 4><<<gN, 256, 0, stream>>>(x, W1, as1, ad1, h, als, ald);
    agg_h4<<<N_NODES / 4, 256, 0, stream>>>(offs, srcs, h, als, ald, b1, g, 1);
    // layer 2: g[100000,64] @ W2[64,64], H=4
    gemm_al<64, 64, 4><<<gN, 256, 0, stream>>>(g, W2, as2, ad2, h, als, ald);
    agg_h4<<<N_NODES / 4, 256, 0, stream>>>(offs, srcs, h, als, ald, b2, g, 1);
    // layer 3: g[100000,64] @ W3[64,32], H=1 -> d_out
    gemm_al<64, 32, 1><<<gN, 256, 0, stream>>>(g, W3, as3, ad3, h, als, ald);
    agg_h1<<<N_NODES / 4, 256, 0, stream>>>(offs, srcs, h, als, ald, b3, out);
}